// Round 6
// baseline (218.482 us; speedup 1.0000x reference)
//
#include <hip/hip_runtime.h>
#include <math.h>

#define B_   2
#define L_   2048
#define D_   1024
#define H_   16
#define HD_  64
#define C_   128
#define N_   16
#define INV_SCALE 0.03125f   // 1/sqrt(1024)
#define SCL2 0.0450842200f   // INV_SCALE * log2(e)

typedef _Float16 h8 __attribute__((ext_vector_type(8)));
typedef _Float16 h4 __attribute__((ext_vector_type(4)));
typedef float    f4 __attribute__((ext_vector_type(4)));

#define MFMA16(a, b, c) __builtin_amdgcn_mfma_f32_16x16x32_f16((a), (b), (c), 0, 0, 0)

#if __has_builtin(__builtin_amdgcn_exp2f)
#define EXP2(x) __builtin_amdgcn_exp2f(x)
#else
#define EXP2(x) exp2f(x)
#endif

__device__ __forceinline__ void gl_lds16(const void* g, void* l) {
  __builtin_amdgcn_global_load_lds(
      (const __attribute__((address_space(1))) void*)g,
      (__attribute__((address_space(3))) void*)l, 16, 0, 0);
}

#define SBAR()  do { __builtin_amdgcn_sched_barrier(0); \
                     __builtin_amdgcn_s_barrier();      \
                     __builtin_amdgcn_sched_barrier(0); } while (0)
#define LGKM0() do { asm volatile("s_waitcnt lgkmcnt(0)" ::: "memory"); \
                     __builtin_amdgcn_sched_barrier(0); } while (0)
#define VMW(n)  do { asm volatile("s_waitcnt vmcnt(" #n ")" ::: "memory"); \
                     __builtin_amdgcn_sched_barrier(0); } while (0)

// ---------------------------------------------------------------------------
// Fused prep: blocks [0,4096) x fp32->fp16; [4096,7168) w_qkv transpose;
// [7168,8192) w_o transpose. All branches wave-uniform per block.
// ---------------------------------------------------------------------------
__global__ __launch_bounds__(256) void prep_kernel(
    const float* __restrict__ X, _Float16* __restrict__ Xh,
    const float* __restrict__ Wq, _Float16* __restrict__ WqT,
    const float* __restrict__ Wo, _Float16* __restrict__ WoT)
{
  __shared__ float ts[32][36];
  const int tid = threadIdx.x;
  const int id = blockIdx.x;
  if (id < 4096) {
    int i = id * 1024 + tid * 4;
    float4 v = *(const float4*)(X + i);
    h4 o = { (_Float16)v.x, (_Float16)v.y, (_Float16)v.z, (_Float16)v.w };
    *(h4*)(Xh + i) = o;
    return;
  }
  const float* W; _Float16* WT; int Nc, bx, by;
  if (id < 7168) {
    int idx = id - 4096;
    W = Wq; WT = WqT; Nc = 3072; bx = idx % 96; by = idx / 96;
  } else {
    int idx = id - 7168;
    W = Wo; WT = WoT; Nc = 1024; bx = idx & 31; by = idx >> 5;
  }
  const int n0 = bx * 32, k0 = by * 32;
  {
    int kr = tid >> 3, nc4 = (tid & 7) * 4;
    float4 v = *(const float4*)&W[(size_t)(k0 + kr) * Nc + n0 + nc4];
    ts[kr][nc4+0] = v.x; ts[kr][nc4+1] = v.y; ts[kr][nc4+2] = v.z; ts[kr][nc4+3] = v.w;
  }
  __syncthreads();
  {
    int nr = tid >> 3, kc4 = (tid & 7) * 4;
    h4 o = { (_Float16)ts[kc4+0][nr], (_Float16)ts[kc4+1][nr],
             (_Float16)ts[kc4+2][nr], (_Float16)ts[kc4+3][nr] };
    *(h4*)&WT[(size_t)(n0 + nr) * 1024 + k0 + kc4] = o;
  }
}

// ---------------------------------------------------------------------------
// QKV GEMM: 256x192 tile, BK=64, 512 threads / 8 waves, 4 phases per K-tile.
// (round-4 schedule, kept)
// ---------------------------------------------------------------------------
__global__ __launch_bounds__(512, 2) void qkv256_kernel(
    const _Float16* __restrict__ A, const _Float16* __restrict__ Bt,
    const float* __restrict__ bias,
    _Float16* __restrict__ Qh, _Float16* __restrict__ Kh, _Float16* __restrict__ VT,
    float* __restrict__ QP, float* __restrict__ KP, float* __restrict__ VCS)
{
  __shared__ __align__(16) _Float16 As[2][16384];
  __shared__ __align__(16) _Float16 Bs[2][12288];

  const int tid = threadIdx.x;
  const int w = tid >> 6, lane = tid & 63;
  const int q = lane >> 4, r = lane & 15, r7 = r & 7;
  const int wm = w >> 2, wn = w & 3;

  const int id = blockIdx.x, xcd = id & 7, slot = id >> 3;
  const int m0 = ((xcd >> 1) * 4 + (slot & 3)) * 256;
  const int n0 = ((xcd & 1) * 8 + (slot >> 2)) * 192;

  const int srow = tid >> 3;
  const int spart = (tid & 7) ^ (srow & 7);
  const _Float16* Asrc = A  + (size_t)(m0 + srow) * 1024 + spart * 8;
  const _Float16* Bsrc = Bt + (size_t)(n0 + srow) * 1024 + spart * 8;
  const int ldst = w * 512;

  const int aoffb = (wm * 128 + r) * 64;
  const int boffb = (wn * 48 + r) * 64;
  const int k0s = (q ^ r7) << 3;
  const int k1s = ((4 + q) ^ r7) << 3;

  auto stA = [&](int cc, int ko, int qq) {
    gl_lds16(Asrc + (size_t)qq * 65536 + ko, &As[cc][qq * 4096 + ldst]);
  };
  auto stB = [&](int cc, int ko, int qq) {
    gl_lds16(Bsrc + (size_t)qq * 65536 + ko, &Bs[cc][qq * 4096 + ldst]);
  };

  f4 acc[8][3];
  #pragma unroll
  for (int m = 0; m < 8; ++m)
    #pragma unroll
    for (int n = 0; n < 3; ++n) acc[m][n] = (f4){0.f, 0.f, 0.f, 0.f};

  stB(0, 0, 0); stB(0, 0, 1); stB(0, 0, 2);
  stA(0, 0, 0); stA(0, 0, 2); stA(0, 0, 1); stA(0, 0, 3);
  VMW(2);
  SBAR();

  for (int t = 0; t < 16; ++t) {
    const int c = t & 1;
    const _Float16* __restrict__ Ab = As[c];
    const _Float16* __restrict__ Bb = Bs[c];
    const int kt = (t + 1) << 6;
    const bool pf = (t < 15);
    h8 af[4], bf[3];

    // ---- phase 1 ----
    #pragma unroll
    for (int m = 0; m < 4; ++m) af[m] = *(const h8*)&Ab[aoffb + m * 1024 + k0s];
    #pragma unroll
    for (int n = 0; n < 3; ++n) bf[n] = *(const h8*)&Bb[boffb + n * 1024 + k0s];
    if (pf) { stB(c ^ 1, kt, 0); stB(c ^ 1, kt, 1); stB(c ^ 1, kt, 2); }
    SBAR();
    LGKM0();
    __builtin_amdgcn_s_setprio(1);
    #pragma unroll
    for (int m = 0; m < 4; ++m)
      #pragma unroll
      for (int n = 0; n < 3; ++n) acc[m][n] = MFMA16(af[m], bf[n], acc[m][n]);
    __builtin_amdgcn_s_setprio(0);
    __builtin_amdgcn_sched_barrier(0);
    if (pf) { VMW(3); } else { VMW(0); }
    SBAR();

    // ---- phase 2 ----
    #pragma unroll
    for (int m = 0; m < 4; ++m) af[m] = *(const h8*)&Ab[aoffb + (4 + m) * 1024 + k0s];
    if (pf) { stA(c ^ 1, kt, 0); stA(c ^ 1, kt, 2); stA(c ^ 1, kt, 1); }
    SBAR();
    LGKM0();
    __builtin_amdgcn_s_setprio(1);
    #pragma unroll
    for (int m = 0; m < 4; ++m)
      #pragma unroll
      for (int n = 0; n < 3; ++n) acc[4 + m][n] = MFMA16(af[m], bf[n], acc[4 + m][n]);
    __builtin_amdgcn_s_setprio(0);
    __builtin_amdgcn_sched_barrier(0);
    SBAR();

    // ---- phase 3 ----
    #pragma unroll
    for (int m = 0; m < 4; ++m) af[m] = *(const h8*)&Ab[aoffb + m * 1024 + k1s];
    #pragma unroll
    for (int n = 0; n < 3; ++n) bf[n] = *(const h8*)&Bb[boffb + n * 1024 + k1s];
    if (pf) { stA(c ^ 1, kt, 3); }
    SBAR();
    LGKM0();
    __builtin_amdgcn_s_setprio(1);
    #pragma unroll
    for (int m = 0; m < 4; ++m)
      #pragma unroll
      for (int n = 0; n < 3; ++n) acc[m][n] = MFMA16(af[m], bf[n], acc[m][n]);
    __builtin_amdgcn_s_setprio(0);
    __builtin_amdgcn_sched_barrier(0);
    SBAR();

    // ---- phase 4 ----
    #pragma unroll
    for (int m = 0; m < 4; ++m) af[m] = *(const h8*)&Ab[aoffb + (4 + m) * 1024 + k1s];
    if (pf) {
      VMW(2);
    }
    SBAR();
    LGKM0();
    __builtin_amdgcn_s_setprio(1);
    #pragma unroll
    for (int m = 0; m < 4; ++m)
      #pragma unroll
      for (int n = 0; n < 3; ++n) acc[4 + m][n] = MFMA16(af[m], bf[n], acc[4 + m][n]);
    __builtin_amdgcn_s_setprio(0);
    __builtin_amdgcn_sched_barrier(0);
    SBAR();
  }

  const int rb = m0 + wm * 128;
  const int b2 = rb >> 11;
  const int nch = (rb & 2047) >> 7;
  #pragma unroll
  for (int tc = 0; tc < 3; ++tc) {
    const int gn = n0 + wn * 48 + tc * 16 + r;
    const float bj = bias[gn];
    const int which = gn >> 10, rem = gn & 1023;
    const int h2 = rem >> 6, d2 = rem & 63;
    if (which < 2) {
      _Float16* dst = which == 0 ? Qh : Kh;
      #pragma unroll
      for (int m = 0; m < 8; ++m)
        #pragma unroll
        for (int i = 0; i < 4; ++i) {
          const int gm = rb + m * 16 + q * 4 + i;
          const int l2 = gm & 2047;
          dst[(((size_t)(b2 * H_ + h2)) * L_ + l2) * HD_ + d2] =
              (_Float16)(acc[m][tc][i] + bj);
        }
    } else {
      #pragma unroll
      for (int m = 0; m < 8; ++m) {
        const int gm0 = rb + m * 16 + q * 4;
        const int l2 = gm0 & 2047;
        h4 hv = { (_Float16)(acc[m][tc][0] + bj), (_Float16)(acc[m][tc][1] + bj),
                  (_Float16)(acc[m][tc][2] + bj), (_Float16)(acc[m][tc][3] + bj) };
        *(h4*)&VT[((size_t)(b2 * H_ + h2) * HD_ + d2) * L_ + l2] = hv;
      }
    }
    float s2 = 0.f;
    #pragma unroll
    for (int m = 0; m < 8; ++m)
      #pragma unroll
      for (int i = 0; i < 4; ++i) s2 += acc[m][tc][i];
    s2 += __shfl_xor(s2, 16);
    s2 += __shfl_xor(s2, 32);
    if (q == 0) {
      const size_t o = (((size_t)(b2 * H_ + h2)) * N_ + nch) * HD_ + d2;
      if (which == 0)      QP[o] = s2 * (1.f / 128.f) + bj;
      else if (which == 1) KP[o] = s2 * (1.f / 128.f) + bj;
      else                 VCS[o] = s2 + 128.f * bj;
    }
  }
}

// ---------------------------------------------------------------------------
// fp16 MFMA GEMM (out-proj only), double-buffered global_load_lds staging.
// ---------------------------------------------------------------------------
template<int MT>
__global__ __launch_bounds__(256, 4) void gemm16_kernel(
    const _Float16* __restrict__ A, const _Float16* __restrict__ Bt,
    const float* __restrict__ bias, float* __restrict__ out, int Kd)
{
  constexpr int SM = MT / 32;
  __shared__ __align__(16) _Float16 As[2][MT * 32];
  __shared__ __align__(16) _Float16 Bs[2][4096];
  const int tid = threadIdx.x;
  const int lane = tid & 63, w = tid >> 6;
  const int q = lane >> 4, r = lane & 15;
  const int mb = (w >> 1) * (MT / 2);
  const int nb = (w & 1) * 64;

  int m0, n0;
  {
    const int id = blockIdx.x;
    const int xcd = id & 7, slot = id >> 3;
    m0 = (xcd * 8 + (slot >> 3)) * 64;
    n0 = (slot & 7) * 128;
  }

  const int Rr = tid >> 2;
  const int cd = (tid & 3) ^ ((Rr >> 1) & 3);
  const _Float16* Ag = A + (size_t)(m0 + Rr) * Kd + cd * 8;
  const _Float16* Bg = Bt + (size_t)(n0 + Rr) * Kd + cd * 8;
  const size_t rowStep = (size_t)64 * Kd;

  f4 acc[SM][4];
  #pragma unroll
  for (int s = 0; s < SM; ++s)
    #pragma unroll
    for (int t = 0; t < 4; ++t) acc[s][t] = (f4){0.f, 0.f, 0.f, 0.f};

  const int nIter = Kd >> 5;
  const int koff = (q ^ ((r >> 1) & 3)) << 3;

  auto stage = [&](int bf, int kt) {
    _Float16* Asl = &As[bf][w * 512];
    _Float16* Bsl = &Bs[bf][w * 512];
    gl_lds16(Ag + kt, Asl);
    if constexpr (MT == 128) gl_lds16(Ag + kt + rowStep, Asl + 2048);
    gl_lds16(Bg + kt, Bsl);
    if constexpr (MT == 128) gl_lds16(Bg + kt + rowStep, Bsl + 2048);
    else gl_lds16(Bg + kt + rowStep, Bsl + 2048);
  };

  stage(0, 0);

  for (int it = 0; it < nIter; ++it) {
    __syncthreads();
    if (it + 1 < nIter) stage((it + 1) & 1, (it + 1) << 5);
    const _Float16* Ab = As[it & 1];
    const _Float16* Bb = Bs[it & 1];
    h8 af[SM], bf4[4];
    #pragma unroll
    for (int s = 0; s < SM; ++s)
      af[s] = *(const h8*)&Ab[(mb + s * 16 + r) * 32 + koff];
    #pragma unroll
    for (int t = 0; t < 4; ++t)
      bf4[t] = *(const h8*)&Bb[(nb + t * 16 + r) * 32 + koff];
    #pragma unroll
    for (int s = 0; s < SM; ++s)
      #pragma unroll
      for (int t = 0; t < 4; ++t)
        acc[s][t] = MFMA16(af[s], bf4[t], acc[s][t]);
  }

  #pragma unroll
  for (int t = 0; t < 4; ++t) {
    int gn = n0 + nb + t * 16 + r;
    float bj = bias[gn];
    #pragma unroll
    for (int s = 0; s < SM; ++s)
      #pragma unroll
      for (int i = 0; i < 4; ++i) {
        int gm = m0 + mb + s * 16 + q * 4 + i;
        out[(size_t)gm * 1024 + gn] = acc[s][t][i] + bj;
      }
  }
}

// ---------------------------------------------------------------------------
// Fused pool2: blocks [0,512) c2t (+ per-chunk max/min); [512,544) csuf.
// ---------------------------------------------------------------------------
__global__ __launch_bounds__(128) void pool2_kernel(
    const float* __restrict__ QP, const _Float16* __restrict__ Kh,
    const float* __restrict__ VCS,
    float* __restrict__ C2T, float* __restrict__ C2TMX, float* __restrict__ C2TMN,
    float* __restrict__ CSUF)
{
  __shared__ float qp_s[64];
  __shared__ float red[4];
  if (blockIdx.x >= 512) {
    int bh = blockIdx.x - 512, d = threadIdx.x;
    if (d < 64) {
      float run = 0.f;
      for (int n = N_ - 1; n >= 0; --n) {
        size_t o = ((size_t)bh * N_ + n) * HD_ + d;
        CSUF[o] = run;
        run += VCS[o];
      }
    }
    return;
  }
  int bh = blockIdx.x >> 4, n = blockIdx.x & 15, tid = threadIdx.x;
  int w = tid >> 6, lane = tid & 63;
  if (tid < 64) qp_s[tid] = QP[((size_t)bh * N_ + n) * HD_ + tid];
  const _Float16* kr = Kh + (((size_t)bh * L_) + n * C_ + tid) * HD_;
  h8 kv[8];
  #pragma unroll
  for (int c8 = 0; c8 < 8; ++c8) kv[c8] = *(const h8*)(kr + c8 * 8);
  __syncthreads();
  float s = 0.f;
  #pragma unroll
  for (int c8 = 0; c8 < 8; ++c8)
    #pragma unroll
    for (int j = 0; j < 8; ++j)
      s = fmaf((float)kv[c8][j], qp_s[c8 * 8 + j], s);
  C2T[((size_t)bh * N_ + n) * C_ + tid] = s;
  float mx = s, mn = s;
  #pragma unroll
  for (int st = 1; st <= 32; st <<= 1) {
    mx = fmaxf(mx, __shfl_xor(mx, st));
    mn = fminf(mn, __shfl_xor(mn, st));
  }
  if (lane == 0) { red[w * 2] = mx; red[w * 2 + 1] = mn; }
  __syncthreads();
  if (tid == 0) {
    C2TMX[bh * N_ + n] = fmaxf(red[0], red[2]);
    C2TMN[bh * N_ + n] = fminf(red[1], red[3]);
  }
}

// ---------------------------------------------------------------------------
// attn6: BARRIER-FREE attention. Round-6 theory: attn4's time was in
// barrier-lockstep serialization (all counters low), and per-XCD working set
// (4 bh x 256KB V + K = 2MB) is L2-resident with 16KB tiles L1-resident for
// 8-wave reuse -- so LDS staging is pure overhead (guide common-mistake #7).
// K/V/KP/C2T/CSUF are read DIRECTLY from global (L1/L2-served, unswizzled
// addresses: the old stage-swizzle + read-swizzle cancel). P stays in LDS but
// is wave-local (same wave writes and reads its 4KB slice) -> ZERO
// __syncthreads in the kernel; waves run free, 16+ waves/CU hide latency.
// LDS 32KB (P only). Balanced chunk map kept (per-CU work = 17 units).
// ---------------------------------------------------------------------------
__global__ __launch_bounds__(512, 4) void attn6_kernel(
    const _Float16* __restrict__ Qh, const _Float16* __restrict__ Kh,
    const _Float16* __restrict__ VT,
    const float* __restrict__ C2T, const float* __restrict__ C2TMX,
    const float* __restrict__ C2TMN, const float* __restrict__ CSUF,
    const float* __restrict__ KP, _Float16* __restrict__ AOh)
{
  __shared__ __align__(16) _Float16 pwb[16384];   // P: 8 waves x 4KB, wave-local

  const int tid = threadIdx.x;
  const int w = tid >> 6, lane = tid & 63;
  const int q = lane >> 4, r = lane & 15;
  const int r7 = r & 7;
  const int id = blockIdx.x;
  const int bh = ((id & 7) << 2) + ((id >> 3) & 3);   // XCD-aware
  const int s5 = id >> 5;                             // 0..15
  const int nq = (s5 < 8) ? (15 - s5) : (s5 - 8);     // balanced pairs sum 17
  const int l0 = nq * 128;
  const int rowA = l0 + w * 16 + r;
  const int pcw = w * 16 + r;
  const size_t bhL = (size_t)bh * L_;
  const int b2 = bh >> 4, h2 = bh & 15;

  // ---- Q rows (global, 2x16B) ----
  h8 qa0 = *(const h8*)(Qh + (bhL + rowA) * HD_ + q * 8);
  h8 qa1 = *(const h8*)(Qh + (bhL + rowA) * HD_ + 32 + q * 8);
  float mxL = C2TMX[bh * N_ + r];
  float mnL = C2TMN[bh * N_ + r];

  // ---- tval via MFMA: A = KP[n=r][d] (f32 global -> fp16), B = Q ----
  f4 tvacc = (f4){0.f, 0.f, 0.f, 0.f};
  {
    const float* kp0 = KP + ((size_t)bh * N_ + r) * HD_ + q * 8;
    float4 a0 = *(const float4*)(kp0);
    float4 a1 = *(const float4*)(kp0 + 4);
    float4 c0 = *(const float4*)(kp0 + 32);
    float4 c1 = *(const float4*)(kp0 + 36);
    h8 kpa0 = { (_Float16)a0.x, (_Float16)a0.y, (_Float16)a0.z, (_Float16)a0.w,
                (_Float16)a1.x, (_Float16)a1.y, (_Float16)a1.z, (_Float16)a1.w };
    h8 kpa1 = { (_Float16)c0.x, (_Float16)c0.y, (_Float16)c0.z, (_Float16)c0.w,
                (_Float16)c1.x, (_Float16)c1.y, (_Float16)c1.z, (_Float16)c1.w };
    tvacc = MFMA16(kpa0, qa0, tvacc);
    tvacc = MFMA16(kpa1, qa1, tvacc);
  }
  float tvs[4];
  #pragma unroll
  for (int i = 0; i < 4; ++i) tvs[i] = tvacc[i] * SCL2;

  // off-diag analytic row max (log2 units)
  float pm = -1e30f;
  #pragma unroll
  for (int i = 0; i < 4; ++i) {
    int n = q * 4 + i;
    float mx = __shfl(mxL, n);
    float mn = __shfl(mnL, n);
    float cm = fmaxf(tvs[i] * mx, tvs[i] * mn);
    pm = (n < nq) ? fmaxf(pm, cm) : pm;
  }
  pm = fmaxf(pm, __shfl_xor(pm, 16));
  pm = fmaxf(pm, __shfl_xor(pm, 32));

  // ---- diag chunk: SWAPPED QK^T, K read direct from global ----
  f4 sc[8];
  #pragma unroll
  for (int u = 0; u < 8; ++u) sc[u] = (f4){0.f, 0.f, 0.f, 0.f};
  {
    const _Float16* kbase = Kh + (bhL + l0 + r) * HD_ + q * 8;
    #pragma unroll
    for (int u = 0; u < 8; ++u) {
      h8 kc0 = *(const h8*)(kbase + u * 16 * HD_);
      h8 kc1 = *(const h8*)(kbase + u * 16 * HD_ + 32);
      sc[u] = MFMA16(kc0, qa0, sc[u]);
      sc[u] = MFMA16(kc1, qa1, sc[u]);
    }
  }

  // mask + per-lane row max (all 32 values belong to qrow r)
  float rm = -1e30f;
  #pragma unroll
  for (int u = 0; u < 8; ++u)
    #pragma unroll
    for (int i = 0; i < 4; ++i) {
      int lcol = u * 16 + q * 4 + i;
      float v = sc[u][i] * SCL2;
      v = (lcol <= pcw) ? v : -1e30f;
      sc[u][i] = v;
      rm = fmaxf(rm, v);
    }
  rm = fmaxf(rm, __shfl_xor(rm, 16));
  rm = fmaxf(rm, __shfl_xor(rm, 32));

  const float M = fmaxf(fmaxf(pm, rm), 0.f);
  const float e0 = EXP2(-M);

  // ---- exp + P-write (wave-local LDS slice; no barrier needed) ----
  _Float16* pw = pwb + w * 2048;
  const int pwbase = r * 128 + ((q & 1) << 2);
  float csl = 0.f;
  #pragma unroll
  for (int u = 0; u < 8; ++u) {
    h4 pv4;
    #pragma unroll
    for (int i = 0; i < 4; ++i) {
      float v = sc[u][i];
      float p = (v > -1e29f) ? EXP2(v - M) : 0.f;
      csl += p;
      pv4[i] = (_Float16)p;
    }
    *(h4*)&pw[pwbase + ((((u << 1) | (q >> 1)) ^ r7) << 3)] = pv4;
  }
  csl += __shfl_xor(csl, 16);
  csl += __shfl_xor(csl, 32);
  float den = csl;

  // ---- PV(diag) + suffix-V, V read direct from global ----
  f4 oacc[4], sacc[4];
  #pragma unroll
  for (int t = 0; t < 4; ++t) {
    oacc[t] = (f4){0.f, 0.f, 0.f, 0.f};
    sacc[t] = (f4){0.f, 0.f, 0.f, 0.f};
  }
  #pragma unroll
  for (int s = 0; s < 4; ++s) {
    h8 pa = *(const h8*)&pw[r * 128 + (((s * 4 + q) ^ r7) << 3)];
    h8 mk;
    #pragma unroll
    for (int j2 = 0; j2 < 8; ++j2)
      mk[j2] = (_Float16)((s * 32 + q * 8 + j2 > pcw) ? 1.f : 0.f);
    #pragma unroll
    for (int t = 0; t < 4; ++t) {
      h8 vb = *(const h8*)(VT + ((size_t)bh * HD_ + t * 16 + r) * L_ +
                           l0 + s * 32 + q * 8);
      oacc[t] = MFMA16(pa, vb, oacc[t]);
      sacc[t] = MFMA16(mk, vb, sacc[t]);    // within-chunk suffix-V
    }
  }

  // ---- off-diagonal chunks: fixed M, all operands direct from global ----
  float dsum = 0.f;
  const float negM = -M;
  for (int n = nq - 1; n >= 0; --n) {
    int i0 = n & 3;
    float tvx = i0 == 0 ? tvs[0] : i0 == 1 ? tvs[1] : i0 == 2 ? tvs[2] : tvs[3];
    float tvn = __shfl(tvx, ((n >> 2) << 4) + r);
    const float* c2p = C2T + ((size_t)bh * N_ + n) * C_;
    const _Float16* vrow = VT + (size_t)bh * HD_ * L_ + n * C_;

    #pragma unroll
    for (int s = 0; s < 4; ++s) {
      f4 cca = *(const f4*)(c2p + s * 32 + q * 8);
      f4 ccb = *(const f4*)(c2p + s * 32 + q * 8 + 4);
      float p0 = EXP2(fmaf(tvn, cca[0], negM)), p1 = EXP2(fmaf(tvn, cca[1], negM));
      float p2 = EXP2(fmaf(tvn, cca[2], negM)), p3 = EXP2(fmaf(tvn, cca[3], negM));
      float p4 = EXP2(fmaf(tvn, ccb[0], negM)), p5 = EXP2(fmaf(tvn, ccb[1], negM));
      float p6 = EXP2(fmaf(tvn, ccb[2], negM)), p7 = EXP2(fmaf(tvn, ccb[3], negM));
      dsum += p0 + p1 + p2 + p3 + p4 + p5 + p6 + p7;
      h8 pa = { (_Float16)p0, (_Float16)p1, (_Float16)p2, (_Float16)p3,
                (_Float16)p4, (_Float16)p5, (_Float16)p6, (_Float16)p7 };
      #pragma unroll
      for (int t = 0; t < 4; ++t) {
        h8 vb = *(const h8*)(vrow + ((size_t)(t * 16 + r)) * L_ +
                             s * 32 + q * 8);
        oacc[t] = MFMA16(pa, vb, oacc[t]);
      }
    }
  }
  dsum += __shfl_xor(dsum, 16);
  dsum += __shfl_xor(dsum, 32);
  den += dsum;

  // ---- masked-zero closed form + output ----
  int cnt = (L_ - 1) - rowA;
  den += e0 * (float)cnt;
  float e0r[4], dnr[4];
  #pragma unroll
  for (int i = 0; i < 4; ++i) {
    e0r[i] = __shfl(e0,  (q << 2) + i);
    dnr[i] = __shfl(den, (q << 2) + i);
  }
  #pragma unroll
  for (int t = 0; t < 4; ++t) {
    int d = t * 16 + r;
    float csf = CSUF[((size_t)bh * N_ + nq) * HD_ + d];
    #pragma unroll
    for (int i = 0; i < 4; ++i) {
      int row = l0 + w * 16 + q * 4 + i;
      float suffix = sacc[t][i] + csf;
      float o = (oacc[t][i] + e0r[i] * suffix) / dnr[i];
      AOh[((size_t)b2 * L_ + row) * D_ + h2 * HD_ + d] = (_Float16)o;
    }
  }
}

// ---------------------------------------------------------------------------
extern "C" void kernel_launch(void* const* d_in, const int* in_sizes, int n_in,
                              void* d_out, int out_size, void* d_ws, size_t ws_size,
                              hipStream_t stream)
{
  (void)in_sizes; (void)n_in; (void)out_size; (void)ws_size;
  const float* x     = (const float*)d_in[0];
  const float* w_qkv = (const float*)d_in[1];
  const float* b_qkv = (const float*)d_in[2];
  const float* w_o   = (const float*)d_in[3];
  const float* b_o   = (const float*)d_in[4];
  float* out = (float*)d_out;

  char* p = (char*)d_ws;
  _Float16* xh   = (_Float16*)p; p += (size_t)4194304 * 2;
  _Float16* wqT  = (_Float16*)p; p += (size_t)3145728 * 2;
  _Float16* woT  = (_Float16*)p; p += (size_t)1048576 * 2;
  _Float16* Qh   = (_Float16*)p; p += (size_t)4194304 * 2;
  _Float16* Kh   = (_Float16*)p; p += (size_t)4194304 * 2;
  _Float16* VT   = (_Float16*)p; p += (size_t)4194304 * 2;
  _Float16* AOh  = (_Float16*)p; p += (size_t)4194304 * 2;
  float*    C2T  = (float*)p;    p += (size_t)65536 * 4;
  float*    QP   = (float*)p;    p += (size_t)32768 * 4;
  float*    KP   = (float*)p;    p += (size_t)32768 * 4;
  float*    VCS  = (float*)p;    p += (size_t)32768 * 4;
  float*    CSUF = (float*)p;    p += (size_t)32768 * 4;
  float*    MXa  = (float*)p;    p += (size_t)512 * 4;
  float*    MNa  = (float*)p;    p += (size_t)512 * 4;

  prep_kernel<<<8192, 256, 0, stream>>>(x, xh, w_qkv, wqT, w_o, woT);
  qkv256_kernel<<<256, 512, 0, stream>>>(
      xh, wqT, b_qkv, Qh, Kh, VT, QP, KP, VCS);
  pool2_kernel<<<544, 128, 0, stream>>>(QP, Kh, VCS, C2T, MXa, MNa, CSUF);
  attn6_kernel<<<512, 512, 0, stream>>>(
      Qh, Kh, VT, C2T, MXa, MNa, CSUF, KP, AOh);
  gemm16_kernel<64><<<512, 256, 0, stream>>>(
      AOh, woT, b_o, out, D_);
}

// Round 7
// 164.256 us; speedup vs baseline: 1.3301x; 1.3301x over previous
//
#include <hip/hip_runtime.h>
#include <math.h>

#define B_   2
#define L_   2048
#define D_   1024
#define H_   16
#define HD_  64
#define C_   128
#define N_   16
#define INV_SCALE 0.03125f   // 1/sqrt(1024)
#define SCL2 0.0450842200f   // INV_SCALE * log2(e)

typedef _Float16 h8 __attribute__((ext_vector_type(8)));
typedef _Float16 h4 __attribute__((ext_vector_type(4)));
typedef float    f4 __attribute__((ext_vector_type(4)));

#define MFMA16(a, b, c) __builtin_amdgcn_mfma_f32_16x16x32_f16((a), (b), (c), 0, 0, 0)

#if __has_builtin(__builtin_amdgcn_exp2f)
#define EXP2(x) __builtin_amdgcn_exp2f(x)
#else
#define EXP2(x) exp2f(x)
#endif

__device__ __forceinline__ void gl_lds16(const void* g, void* l) {
  __builtin_amdgcn_global_load_lds(
      (const __attribute__((address_space(1))) void*)g,
      (__attribute__((address_space(3))) void*)l, 16, 0, 0);
}

#define SBAR()  do { __builtin_amdgcn_sched_barrier(0); \
                     __builtin_amdgcn_s_barrier();      \
                     __builtin_amdgcn_sched_barrier(0); } while (0)
#define LGKM0() do { asm volatile("s_waitcnt lgkmcnt(0)" ::: "memory"); \
                     __builtin_amdgcn_sched_barrier(0); } while (0)
#define VMW(n)  do { asm volatile("s_waitcnt vmcnt(" #n ")" ::: "memory"); \
                     __builtin_amdgcn_sched_barrier(0); } while (0)

// ---------------------------------------------------------------------------
// Fused prep: blocks [0,4096) x fp32->fp16; [4096,7168) w_qkv transpose;
// [7168,8192) w_o transpose. All branches wave-uniform per block.
// ---------------------------------------------------------------------------
__global__ __launch_bounds__(256) void prep_kernel(
    const float* __restrict__ X, _Float16* __restrict__ Xh,
    const float* __restrict__ Wq, _Float16* __restrict__ WqT,
    const float* __restrict__ Wo, _Float16* __restrict__ WoT)
{
  __shared__ float ts[32][36];
  const int tid = threadIdx.x;
  const int id = blockIdx.x;
  if (id < 4096) {
    int i = id * 1024 + tid * 4;
    float4 v = *(const float4*)(X + i);
    h4 o = { (_Float16)v.x, (_Float16)v.y, (_Float16)v.z, (_Float16)v.w };
    *(h4*)(Xh + i) = o;
    return;
  }
  const float* W; _Float16* WT; int Nc, bx, by;
  if (id < 7168) {
    int idx = id - 4096;
    W = Wq; WT = WqT; Nc = 3072; bx = idx % 96; by = idx / 96;
  } else {
    int idx = id - 7168;
    W = Wo; WT = WoT; Nc = 1024; bx = idx & 31; by = idx >> 5;
  }
  const int n0 = bx * 32, k0 = by * 32;
  {
    int kr = tid >> 3, nc4 = (tid & 7) * 4;
    float4 v = *(const float4*)&W[(size_t)(k0 + kr) * Nc + n0 + nc4];
    ts[kr][nc4+0] = v.x; ts[kr][nc4+1] = v.y; ts[kr][nc4+2] = v.z; ts[kr][nc4+3] = v.w;
  }
  __syncthreads();
  {
    int nr = tid >> 3, kc4 = (tid & 7) * 4;
    h4 o = { (_Float16)ts[kc4+0][nr], (_Float16)ts[kc4+1][nr],
             (_Float16)ts[kc4+2][nr], (_Float16)ts[kc4+3][nr] };
    *(h4*)&WT[(size_t)(n0 + nr) * 1024 + k0 + kc4] = o;
  }
}

// ---------------------------------------------------------------------------
// QKV GEMM: 256x192 tile, BK=64, 512 threads / 8 waves.
// Round-7: 2 phases per K-tile (split by m-half, both k-halves per phase)
// -> 24 MFMA per barrier pair (was 12), 4 SBAR/tile (was 8), B-fragments
// read once and reused across k-halves. Counted vmcnt unchanged in spirit:
//   P1 issues B0,B1,B2,A0,A2(t+1); ends VMW(5) draining A1,A3(t).
//   P2 issues A1,A3(t+1);          ends VMW(2) draining B+A0,A2(t+1).
// (P1 reads A0/A2+B, P2 reads A1/A3 -- quarter mapping: wave wm=0 P1 rows
//  0..63 = A0, P2 rows 64..127 = A1; wm=1 P1 = A2, P2 = A3.)
// ---------------------------------------------------------------------------
__global__ __launch_bounds__(512, 2) void qkv256_kernel(
    const _Float16* __restrict__ A, const _Float16* __restrict__ Bt,
    const float* __restrict__ bias,
    _Float16* __restrict__ Qh, _Float16* __restrict__ Kh, _Float16* __restrict__ VT,
    float* __restrict__ QP, float* __restrict__ KP, float* __restrict__ VCS)
{
  __shared__ __align__(16) _Float16 As[2][16384];
  __shared__ __align__(16) _Float16 Bs[2][12288];

  const int tid = threadIdx.x;
  const int w = tid >> 6, lane = tid & 63;
  const int q = lane >> 4, r = lane & 15, r7 = r & 7;
  const int wm = w >> 2, wn = w & 3;

  const int id = blockIdx.x, xcd = id & 7, slot = id >> 3;
  const int m0 = ((xcd >> 1) * 4 + (slot & 3)) * 256;
  const int n0 = ((xcd & 1) * 8 + (slot >> 2)) * 192;

  const int srow = tid >> 3;
  const int spart = (tid & 7) ^ (srow & 7);
  const _Float16* Asrc = A  + (size_t)(m0 + srow) * 1024 + spart * 8;
  const _Float16* Bsrc = Bt + (size_t)(n0 + srow) * 1024 + spart * 8;
  const int ldst = w * 512;

  const int aoffb = (wm * 128 + r) * 64;
  const int boffb = (wn * 48 + r) * 64;
  const int k0s = (q ^ r7) << 3;
  const int k1s = ((4 + q) ^ r7) << 3;

  auto stA = [&](int cc, int ko, int qq) {
    gl_lds16(Asrc + (size_t)qq * 65536 + ko, &As[cc][qq * 4096 + ldst]);
  };
  auto stB = [&](int cc, int ko, int qq) {
    gl_lds16(Bsrc + (size_t)qq * 65536 + ko, &Bs[cc][qq * 4096 + ldst]);
  };

  f4 acc[8][3];
  #pragma unroll
  for (int m = 0; m < 8; ++m)
    #pragma unroll
    for (int n = 0; n < 3; ++n) acc[m][n] = (f4){0.f, 0.f, 0.f, 0.f};

  // prologue: tile 0, same per-thread order as steady state
  stB(0, 0, 0); stB(0, 0, 1); stB(0, 0, 2);
  stA(0, 0, 0); stA(0, 0, 2); stA(0, 0, 1); stA(0, 0, 3);
  VMW(2);        // drain B0-2,A0,A2(0); A1,A3(0) stay in flight
  SBAR();

  for (int t = 0; t < 16; ++t) {
    const int c = t & 1;
    const _Float16* __restrict__ Ab = As[c];
    const _Float16* __restrict__ Bb = Bs[c];
    const int kt = (t + 1) << 6;
    const bool pf = (t < 15);
    h8 af0[4], af1[4], bf0[3], bf1[3];

    // ---- phase 1: m0-3, k0+k1 ----
    #pragma unroll
    for (int m = 0; m < 4; ++m) {
      af0[m] = *(const h8*)&Ab[aoffb + m * 1024 + k0s];
      af1[m] = *(const h8*)&Ab[aoffb + m * 1024 + k1s];
    }
    #pragma unroll
    for (int n = 0; n < 3; ++n) {
      bf0[n] = *(const h8*)&Bb[boffb + n * 1024 + k0s];
      bf1[n] = *(const h8*)&Bb[boffb + n * 1024 + k1s];
    }
    if (pf) {
      stB(c ^ 1, kt, 0); stB(c ^ 1, kt, 1); stB(c ^ 1, kt, 2);
      stA(c ^ 1, kt, 0); stA(c ^ 1, kt, 2);
    }
    SBAR();
    LGKM0();
    __builtin_amdgcn_s_setprio(1);
    #pragma unroll
    for (int m = 0; m < 4; ++m)
      #pragma unroll
      for (int n = 0; n < 3; ++n) {
        acc[m][n] = MFMA16(af0[m], bf0[n], acc[m][n]);
        acc[m][n] = MFMA16(af1[m], bf1[n], acc[m][n]);
      }
    __builtin_amdgcn_s_setprio(0);
    __builtin_amdgcn_sched_barrier(0);
    if (pf) { VMW(5); } else { VMW(0); }   // drain A1,A3(t) before P2 reads
    SBAR();

    // ---- phase 2: m4-7, k0+k1 (bf reused) ----
    #pragma unroll
    for (int m = 0; m < 4; ++m) {
      af0[m] = *(const h8*)&Ab[aoffb + (4 + m) * 1024 + k0s];
      af1[m] = *(const h8*)&Ab[aoffb + (4 + m) * 1024 + k1s];
    }
    if (pf) { stA(c ^ 1, kt, 1); stA(c ^ 1, kt, 3); }
    SBAR();
    LGKM0();
    __builtin_amdgcn_s_setprio(1);
    #pragma unroll
    for (int m = 0; m < 4; ++m)
      #pragma unroll
      for (int n = 0; n < 3; ++n) {
        acc[4 + m][n] = MFMA16(af0[m], bf0[n], acc[4 + m][n]);
        acc[4 + m][n] = MFMA16(af1[m], bf1[n], acc[4 + m][n]);
      }
    __builtin_amdgcn_s_setprio(0);
    __builtin_amdgcn_sched_barrier(0);
    if (pf) { VMW(2); } else { VMW(0); }   // drain B+A0,A2(t+1) for next P1
    SBAR();
  }

  const int rb = m0 + wm * 128;
  const int b2 = rb >> 11;
  const int nch = (rb & 2047) >> 7;
  #pragma unroll
  for (int tc = 0; tc < 3; ++tc) {
    const int gn = n0 + wn * 48 + tc * 16 + r;
    const float bj = bias[gn];
    const int which = gn >> 10, rem = gn & 1023;
    const int h2 = rem >> 6, d2 = rem & 63;
    if (which < 2) {
      _Float16* dst = which == 0 ? Qh : Kh;
      #pragma unroll
      for (int m = 0; m < 8; ++m)
        #pragma unroll
        for (int i = 0; i < 4; ++i) {
          const int gm = rb + m * 16 + q * 4 + i;
          const int l2 = gm & 2047;
          dst[(((size_t)(b2 * H_ + h2)) * L_ + l2) * HD_ + d2] =
              (_Float16)(acc[m][tc][i] + bj);
        }
    } else {
      #pragma unroll
      for (int m = 0; m < 8; ++m) {
        const int gm0 = rb + m * 16 + q * 4;
        const int l2 = gm0 & 2047;
        h4 hv = { (_Float16)(acc[m][tc][0] + bj), (_Float16)(acc[m][tc][1] + bj),
                  (_Float16)(acc[m][tc][2] + bj), (_Float16)(acc[m][tc][3] + bj) };
        *(h4*)&VT[((size_t)(b2 * H_ + h2) * HD_ + d2) * L_ + l2] = hv;
      }
    }
    float s2 = 0.f;
    #pragma unroll
    for (int m = 0; m < 8; ++m)
      #pragma unroll
      for (int i = 0; i < 4; ++i) s2 += acc[m][tc][i];
    s2 += __shfl_xor(s2, 16);
    s2 += __shfl_xor(s2, 32);
    if (q == 0) {
      const size_t o = (((size_t)(b2 * H_ + h2)) * N_ + nch) * HD_ + d2;
      if (which == 0)      QP[o] = s2 * (1.f / 128.f) + bj;
      else if (which == 1) KP[o] = s2 * (1.f / 128.f) + bj;
      else                 VCS[o] = s2 + 128.f * bj;
    }
  }
}

// ---------------------------------------------------------------------------
// fp16 MFMA GEMM (out-proj only), double-buffered global_load_lds staging.
// ---------------------------------------------------------------------------
template<int MT>
__global__ __launch_bounds__(256, 4) void gemm16_kernel(
    const _Float16* __restrict__ A, const _Float16* __restrict__ Bt,
    const float* __restrict__ bias, float* __restrict__ out, int Kd)
{
  constexpr int SM = MT / 32;
  __shared__ __align__(16) _Float16 As[2][MT * 32];
  __shared__ __align__(16) _Float16 Bs[2][4096];
  const int tid = threadIdx.x;
  const int lane = tid & 63, w = tid >> 6;
  const int q = lane >> 4, r = lane & 15;
  const int mb = (w >> 1) * (MT / 2);
  const int nb = (w & 1) * 64;

  int m0, n0;
  {
    const int id = blockIdx.x;
    const int xcd = id & 7, slot = id >> 3;
    m0 = (xcd * 8 + (slot >> 3)) * 64;
    n0 = (slot & 7) * 128;
  }

  const int Rr = tid >> 2;
  const int cd = (tid & 3) ^ ((Rr >> 1) & 3);
  const _Float16* Ag = A + (size_t)(m0 + Rr) * Kd + cd * 8;
  const _Float16* Bg = Bt + (size_t)(n0 + Rr) * Kd + cd * 8;
  const size_t rowStep = (size_t)64 * Kd;

  f4 acc[SM][4];
  #pragma unroll
  for (int s = 0; s < SM; ++s)
    #pragma unroll
    for (int t = 0; t < 4; ++t) acc[s][t] = (f4){0.f, 0.f, 0.f, 0.f};

  const int nIter = Kd >> 5;
  const int koff = (q ^ ((r >> 1) & 3)) << 3;

  auto stage = [&](int bf, int kt) {
    _Float16* Asl = &As[bf][w * 512];
    _Float16* Bsl = &Bs[bf][w * 512];
    gl_lds16(Ag + kt, Asl);
    if constexpr (MT == 128) gl_lds16(Ag + kt + rowStep, Asl + 2048);
    gl_lds16(Bg + kt, Bsl);
    gl_lds16(Bg + kt + rowStep, Bsl + 2048);
  };

  stage(0, 0);

  for (int it = 0; it < nIter; ++it) {
    __syncthreads();
    if (it + 1 < nIter) stage((it + 1) & 1, (it + 1) << 5);
    const _Float16* Ab = As[it & 1];
    const _Float16* Bb = Bs[it & 1];
    h8 af[SM], bf4[4];
    #pragma unroll
    for (int s = 0; s < SM; ++s)
      af[s] = *(const h8*)&Ab[(mb + s * 16 + r) * 32 + koff];
    #pragma unroll
    for (int t = 0; t < 4; ++t)
      bf4[t] = *(const h8*)&Bb[(nb + t * 16 + r) * 32 + koff];
    #pragma unroll
    for (int s = 0; s < SM; ++s)
      #pragma unroll
      for (int t = 0; t < 4; ++t)
        acc[s][t] = MFMA16(af[s], bf4[t], acc[s][t]);
  }

  #pragma unroll
  for (int t = 0; t < 4; ++t) {
    int gn = n0 + nb + t * 16 + r;
    float bj = bias[gn];
    #pragma unroll
    for (int s = 0; s < SM; ++s)
      #pragma unroll
      for (int i = 0; i < 4; ++i) {
        int gm = m0 + mb + s * 16 + q * 4 + i;
        out[(size_t)gm * 1024 + gn] = acc[s][t][i] + bj;
      }
  }
}

// ---------------------------------------------------------------------------
// Fused pool2: blocks [0,512) c2t (+ per-chunk max/min); [512,544) csuf.
// ---------------------------------------------------------------------------
__global__ __launch_bounds__(128) void pool2_kernel(
    const float* __restrict__ QP, const _Float16* __restrict__ Kh,
    const float* __restrict__ VCS,
    float* __restrict__ C2T, float* __restrict__ C2TMX, float* __restrict__ C2TMN,
    float* __restrict__ CSUF)
{
  __shared__ float qp_s[64];
  __shared__ float red[4];
  if (blockIdx.x >= 512) {
    int bh = blockIdx.x - 512, d = threadIdx.x;
    if (d < 64) {
      float run = 0.f;
      for (int n = N_ - 1; n >= 0; --n) {
        size_t o = ((size_t)bh * N_ + n) * HD_ + d;
        CSUF[o] = run;
        run += VCS[o];
      }
    }
    return;
  }
  int bh = blockIdx.x >> 4, n = blockIdx.x & 15, tid = threadIdx.x;
  int w = tid >> 6, lane = tid & 63;
  if (tid < 64) qp_s[tid] = QP[((size_t)bh * N_ + n) * HD_ + tid];
  const _Float16* kr = Kh + (((size_t)bh * L_) + n * C_ + tid) * HD_;
  h8 kv[8];
  #pragma unroll
  for (int c8 = 0; c8 < 8; ++c8) kv[c8] = *(const h8*)(kr + c8 * 8);
  __syncthreads();
  float s = 0.f;
  #pragma unroll
  for (int c8 = 0; c8 < 8; ++c8)
    #pragma unroll
    for (int j = 0; j < 8; ++j)
      s = fmaf((float)kv[c8][j], qp_s[c8 * 8 + j], s);
  C2T[((size_t)bh * N_ + n) * C_ + tid] = s;
  float mx = s, mn = s;
  #pragma unroll
  for (int st = 1; st <= 32; st <<= 1) {
    mx = fmaxf(mx, __shfl_xor(mx, st));
    mn = fminf(mn, __shfl_xor(mn, st));
  }
  if (lane == 0) { red[w * 2] = mx; red[w * 2 + 1] = mn; }
  __syncthreads();
  if (tid == 0) {
    C2TMX[bh * N_ + n] = fmaxf(red[0], red[2]);
    C2TMN[bh * N_ + n] = fminf(red[1], red[3]);
  }
}

// ---------------------------------------------------------------------------
// One-pass MFMA attention (round-5 attn4, restored verbatim after attn6's
// direct-global experiment regressed 2.2x -- LDS staging IS the 8-wave reuse
// amplifier). Balanced chunk map: per-CU work = 17 units for every CU.
// ---------------------------------------------------------------------------
__global__ __launch_bounds__(512, 4) void attn4_kernel(
    const _Float16* __restrict__ Qh, const _Float16* __restrict__ Kh,
    const _Float16* __restrict__ VT,
    const float* __restrict__ C2T, const float* __restrict__ C2TMX,
    const float* __restrict__ C2TMN, const float* __restrict__ CSUF,
    const float* __restrict__ KP, _Float16* __restrict__ AOh)
{
  __shared__ __align__(16) _Float16 buf0[8192];
  __shared__ __align__(16) _Float16 buf1[8192];
  __shared__ __align__(16) _Float16 buf2[8192];
  __shared__ __align__(16) _Float16 kp_s[1024];
  __shared__ __align__(16) float c2t_s[2][128];

  const int tid = threadIdx.x;
  const int w = tid >> 6, lane = tid & 63;
  const int q = lane >> 4, r = lane & 15;
  const int r7 = r & 7;
  const int id = blockIdx.x;
  const int bh = ((id & 7) << 2) + ((id >> 3) & 3);   // XCD-aware
  const int s5 = id >> 5;                             // 0..15
  const int nq = (s5 < 8) ? (15 - s5) : (s5 - 8);     // balanced pairs sum 17
  const int l0 = nq * 128;
  const int rowA = l0 + w * 16 + r;
  const int pcw = w * 16 + r;
  const size_t bhL = (size_t)bh * L_;
  const int b2 = bh >> 4, h2 = bh & 15;

  auto stageV = [&](_Float16* buf, int n) {
    #pragma unroll
    for (int j2 = 0; j2 < 2; ++j2) {
      int f = j2 * 512 + tid;
      int d = f >> 4, p = f & 15;
      int c16 = p ^ (d & 7);
      gl_lds16(VT + ((size_t)bh * HD_ + d) * L_ + n * C_ + c16 * 8,
               buf + (size_t)(j2 * 512 + w * 64) * 8);
    }
  };
  auto stageK = [&](_Float16* buf, int n) {
    #pragma unroll
    for (int j2 = 0; j2 < 2; ++j2) {
      int f = j2 * 512 + tid;
      int c = f >> 3, p = f & 7;
      int ck = p ^ (c & 7);
      gl_lds16(Kh + (bhL + n * C_ + c) * HD_ + ck * 8,
               buf + (size_t)(j2 * 512 + w * 64) * 8);
    }
  };
  auto stageC = [&](int bf, int n) {
    if (tid < 32)
      gl_lds16(C2T + ((size_t)bh * N_ + n) * C_ + tid * 4, &c2t_s[bf][0]);
  };

  // ---- prologue ----
  if (tid < 256) {
    int n4 = tid >> 4, d4 = (tid & 15) * 4;
    float4 kpv = *(const float4*)&KP[((size_t)bh * N_ + n4) * HD_ + d4];
    int sd = ((((d4 >> 3) ^ (n4 & 7)) << 3) | (d4 & 7));
    h4 hv = { (_Float16)kpv.x, (_Float16)kpv.y, (_Float16)kpv.z, (_Float16)kpv.w };
    *(h4*)&kp_s[n4 * 64 + sd] = hv;
  }
  h8 qa0 = *(const h8*)(Qh + (bhL + rowA) * HD_ + q * 8);
  h8 qa1 = *(const h8*)(Qh + (bhL + rowA) * HD_ + 32 + q * 8);
  float mxL = C2TMX[bh * N_ + r];
  float mnL = C2TMN[bh * N_ + r];
  stageK(buf0, nq);
  stageV(buf2, nq);
  if (nq >= 1) stageC(0, nq - 1);
  __syncthreads();

  // ---- tval via MFMA (log2-scaled) ----
  f4 tvacc = (f4){0.f, 0.f, 0.f, 0.f};
  {
    h8 kpa0 = *(const h8*)&kp_s[r * 64 + ((q ^ r7) << 3)];
    h8 kpa1 = *(const h8*)&kp_s[r * 64 + (((4 + q) ^ r7) << 3)];
    tvacc = MFMA16(kpa0, qa0, tvacc);
    tvacc = MFMA16(kpa1, qa1, tvacc);
  }
  float tvs[4];
  #pragma unroll
  for (int i = 0; i < 4; ++i) tvs[i] = tvacc[i] * SCL2;

  // off-diag analytic row max (log2 units)
  float pm = -1e30f;
  #pragma unroll
  for (int i = 0; i < 4; ++i) {
    int n = q * 4 + i;
    float mx = __shfl(mxL, n);
    float mn = __shfl(mnL, n);
    float cm = fmaxf(tvs[i] * mx, tvs[i] * mn);
    pm = (n < nq) ? fmaxf(pm, cm) : pm;
  }
  pm = fmaxf(pm, __shfl_xor(pm, 16));
  pm = fmaxf(pm, __shfl_xor(pm, 32));

  // ---- diag chunk: SWAPPED QK^T ----
  f4 sc[8];
  #pragma unroll
  for (int u = 0; u < 8; ++u) sc[u] = (f4){0.f, 0.f, 0.f, 0.f};
  {
    h8 kc0 = *(const h8*)&buf0[r * 64 + ((q ^ r7) << 3)];
    h8 kc1 = *(const h8*)&buf0[r * 64 + (((4 + q) ^ r7) << 3)];
    #pragma unroll
    for (int u = 0; u < 8; ++u) {
      h8 kn0, kn1;
      if (u < 7) {
        kn0 = *(const h8*)&buf0[((u + 1) * 16 + r) * 64 + ((q ^ r7) << 3)];
        kn1 = *(const h8*)&buf0[((u + 1) * 16 + r) * 64 + (((4 + q) ^ r7) << 3)];
      }
      sc[u] = MFMA16(kc0, qa0, sc[u]);
      sc[u] = MFMA16(kc1, qa1, sc[u]);
      kc0 = kn0; kc1 = kn1;
    }
  }

  // mask + per-lane row max
  float rm = -1e30f;
  #pragma unroll
  for (int u = 0; u < 8; ++u)
    #pragma unroll
    for (int i = 0; i < 4; ++i) {
      int lcol = u * 16 + q * 4 + i;
      float v = sc[u][i] * SCL2;
      v = (lcol <= pcw) ? v : -1e30f;
      sc[u][i] = v;
      rm = fmaxf(rm, v);
    }
  rm = fmaxf(rm, __shfl_xor(rm, 16));
  rm = fmaxf(rm, __shfl_xor(rm, 32));

  const float M = fmaxf(fmaxf(pm, rm), 0.f);
  const float e0 = EXP2(-M);

  __syncthreads();   // all K/kp reads done; V(diag) staged; P overlay safe

  // exp + P-write (h4 per u, block-XOR swizzle)
  _Float16* pw = (w < 4) ? (buf0 + w * 2048) : (buf1 + (w - 4) * 2048);
  const int pwbase = r * 128 + ((q & 1) << 2);
  float csl = 0.f;
  #pragma unroll
  for (int u = 0; u < 8; ++u) {
    h4 pv4;
    #pragma unroll
    for (int i = 0; i < 4; ++i) {
      float v = sc[u][i];
      float p = (v > -1e29f) ? EXP2(v - M) : 0.f;
      csl += p;
      pv4[i] = (_Float16)p;
    }
    *(h4*)&pw[pwbase + ((((u << 1) | (q >> 1)) ^ r7) << 3)] = pv4;
  }
  csl += __shfl_xor(csl, 16);
  csl += __shfl_xor(csl, 32);
  float den = csl;

  // ---- PV(diag) + suffix-V, pipelined pa/vb reads ----
  f4 oacc[4], sacc[4];
  #pragma unroll
  for (int t = 0; t < 4; ++t) {
    oacc[t] = (f4){0.f, 0.f, 0.f, 0.f};
    sacc[t] = (f4){0.f, 0.f, 0.f, 0.f};
  }
  {
    h8 pcur = *(const h8*)&pw[r * 128 + ((q ^ r7) << 3)];
    h8 vcur[4];
    #pragma unroll
    for (int t = 0; t < 4; ++t)
      vcur[t] = *(const h8*)&buf2[(t * 16 + r) * 128 + ((q ^ r7) << 3)];
    #pragma unroll
    for (int s = 0; s < 4; ++s) {
      h8 pnxt; h8 vnxt[4];
      if (s < 3) {
        pnxt = *(const h8*)&pw[r * 128 + ((((s + 1) * 4 + q) ^ r7) << 3)];
        #pragma unroll
        for (int t = 0; t < 4; ++t)
          vnxt[t] = *(const h8*)&buf2[(t * 16 + r) * 128 + ((((s + 1) * 4 + q) ^ r7) << 3)];
      }
      h8 mk;
      #pragma unroll
      for (int j2 = 0; j2 < 8; ++j2)
        mk[j2] = (_Float16)((s * 32 + q * 8 + j2 > pcw) ? 1.f : 0.f);
      #pragma unroll
      for (int t = 0; t < 4; ++t) {
        oacc[t] = MFMA16(pcur, vcur[t], oacc[t]);
        sacc[t] = MFMA16(mk, vcur[t], sacc[t]);    // within-chunk suffix-V
      }
      pcur = pnxt;
      #pragma unroll
      for (int t = 0; t < 4; ++t) vcur[t] = vnxt[t];
    }
  }

  __syncthreads();   // P/V(diag) reads done
  if (nq >= 1) stageV(buf1, nq - 1);

  // ---- off-diagonal chunks, fixed M, per-lane dsum, pipelined LDS reads ----
  float dsum = 0.f;
  const float negM = -M;
  for (int n = nq - 1; n >= 0; --n) {
    const int k = nq - 1 - n;
    const _Float16* curb = (k & 1) ? buf2 : buf1;
    __syncthreads();
    if (n >= 1) {
      stageV((k & 1) ? buf1 : buf2, n - 1);
      stageC((k + 1) & 1, n - 1);
    }
    int i0 = n & 3;
    float tvx = i0 == 0 ? tvs[0] : i0 == 1 ? tvs[1] : i0 == 2 ? tvs[2] : tvs[3];
    float tvn = __shfl(tvx, ((n >> 2) << 4) + r);
    const float* c2p = c2t_s[k & 1];

    f4 cca = *(const f4*)&c2p[q * 8];
    f4 ccb = *(const f4*)&c2p[q * 8 + 4];
    h8 vcur[4];
    #pragma unroll
    for (int t = 0; t < 4; ++t)
      vcur[t] = *(const h8*)&curb[(t * 16 + r) * 128 + ((q ^ r7) << 3)];

    #pragma unroll
    for (int s = 0; s < 4; ++s) {
      f4 can, cbn; h8 vnxt[4];
      if (s < 3) {
        can = *(const f4*)&c2p[(s + 1) * 32 + q * 8];
        cbn = *(const f4*)&c2p[(s + 1) * 32 + q * 8 + 4];
        #pragma unroll
        for (int t = 0; t < 4; ++t)
          vnxt[t] = *(const h8*)&curb[(t * 16 + r) * 128 + ((((s + 1) * 4 + q) ^ r7) << 3)];
      }
      float p0 = EXP2(fmaf(tvn, cca[0], negM)), p1 = EXP2(fmaf(tvn, cca[1], negM));
      float p2 = EXP2(fmaf(tvn, cca[2], negM)), p3 = EXP2(fmaf(tvn, cca[3], negM));
      float p4 = EXP2(fmaf(tvn, ccb[0], negM)), p5 = EXP2(fmaf(tvn, ccb[1], negM));
      float p6 = EXP2(fmaf(tvn, ccb[2], negM)), p7 = EXP2(fmaf(tvn, ccb[3], negM));
      dsum += p0 + p1 + p2 + p3 + p4 + p5 + p6 + p7;
      h8 pa = { (_Float16)p0, (_Float16)p1, (_Float16)p2, (_Float16)p3,
                (_Float16)p4, (_Float16)p5, (_Float16)p6, (_Float16)p7 };
      #pragma unroll
      for (int t = 0; t < 4; ++t)
        oacc[t] = MFMA16(pa, vcur[t], oacc[t]);
      cca = can; ccb = cbn;
      #pragma unroll
      for (int t = 0; t < 4; ++t) vcur[t] = vnxt[t];
    }
  }
  dsum += __shfl_xor(dsum, 16);
  dsum += __shfl_xor(dsum, 32);
  den += dsum;

  // ---- masked-zero closed form + output ----
  int cnt = (L_ - 1) - rowA;
  den += e0 * (float)cnt;
  float e0r[4], dnr[4];
  #pragma unroll
  for (int i = 0; i < 4; ++i) {
    e0r[i] = __shfl(e0,  (q << 2) + i);
    dnr[i] = __shfl(den, (q << 2) + i);
  }
  #pragma unroll
  for (int t = 0; t < 4; ++t) {
    int d = t * 16 + r;
    float csf = CSUF[((size_t)bh * N_ + nq) * HD_ + d];
    #pragma unroll
    for (int i = 0; i < 4; ++i) {
      int row = l0 + w * 16 + q * 4 + i;
      float suffix = sacc[t][i] + csf;
      float o = (oacc[t][i] + e0r[i] * suffix) / dnr[i];
      AOh[((size_t)b2 * L_ + row) * D_ + h2 * HD_ + d] = (_Float16)o;
    }
  }
}

// ---------------------------------------------------------------------------
extern "C" void kernel_launch(void* const* d_in, const int* in_sizes, int n_in,
                              void* d_out, int out_size, void* d_ws, size_t ws_size,
                              hipStream_t stream)
{
  (void)in_sizes; (void)n_in; (void)out_size; (void)ws_size;
  const float* x     = (const float*)d_in[0];
  const float* w_qkv = (const float*)d_in[1];
  const float* b_qkv = (const float*)d_in[2];
  const float* w_o   = (const float*)d_in[3];
  const float* b_o   = (const float*)d_in[4];
  float* out = (float*)d_out;

  char* p = (char*)d_ws;
  _Float16* xh   = (_Float16*)p; p += (size_t)4194304 * 2;
  _Float16* wqT  = (_Float16*)p; p += (size_t)3145728 * 2;
  _Float16* woT  = (_Float16*)p; p += (size_t)1048576 * 2;
  _Float16* Qh   = (_Float16*)p; p += (size_t)4194304 * 2;
  _Float16* Kh   = (_Float16*)p; p += (size_t)4194304 * 2;
  _Float16* VT   = (_Float16*)p; p += (size_t)4194304 * 2;
  _Float16* AOh  = (_Float16*)p; p += (size_t)4194304 * 2;
  float*    C2T  = (float*)p;    p += (size_t)65536 * 4;
  float*    QP   = (float*)p;    p += (size_t)32768 * 4;
  float*    KP   = (float*)p;    p += (size_t)32768 * 4;
  float*    VCS  = (float*)p;    p += (size_t)32768 * 4;
  float*    CSUF = (float*)p;    p += (size_t)32768 * 4;
  float*    MXa  = (float*)p;    p += (size_t)512 * 4;
  float*    MNa  = (float*)p;    p += (size_t)512 * 4;

  prep_kernel<<<8192, 256, 0, stream>>>(x, xh, w_qkv, wqT, w_o, woT);
  qkv256_kernel<<<256, 512, 0, stream>>>(
      xh, wqT, b_qkv, Qh, Kh, VT, QP, KP, VCS);
  pool2_kernel<<<544, 128, 0, stream>>>(QP, Kh, VCS, C2T, MXa, MNa, CSUF);
  attn4_kernel<<<512, 512, 0, stream>>>(
      Qh, Kh, VT, C2T, MXa, MNa, CSUF, KP, AOh);
  gemm16_kernel<64><<<512, 256, 0, stream>>>(
      AOh, woT, b_o, out, D_);
}